// Round 1
// baseline (617.464 us; speedup 1.0000x reference)
//
#include <hip/hip_runtime.h>
#include <stdint.h>

#define HID 1024
#define NEXP 8
#define NTOK 16384
#define CAP 8192

typedef __attribute__((ext_vector_type(8))) __bf16 bf16x8;
typedef __attribute__((ext_vector_type(8))) short short8;
typedef __attribute__((ext_vector_type(4))) float f32x4;

__device__ __forceinline__ ushort f2bf(float f) {
  uint32_t u = __builtin_bit_cast(uint32_t, f);
  u += 0x7FFF + ((u >> 16) & 1);          // round-to-nearest-even
  return (ushort)(u >> 16);
}
__device__ __forceinline__ float bf2f(ushort u) {
  return __builtin_bit_cast(float, (uint32_t)u << 16);
}

__device__ __forceinline__ void gl16(const void* g, void* l) {
  __builtin_amdgcn_global_load_lds((__attribute__((address_space(1))) void*)(g),
                                   (__attribute__((address_space(3))) void*)(l),
                                   16, 0, 0);
}

// ---------------- fp32 -> bf16 conversion ----------------
__global__ void cvt_kernel(const float* __restrict__ src, ushort* __restrict__ dst, int n4) {
  int i = blockIdx.x * blockDim.x + threadIdx.x;
  int stride = gridDim.x * blockDim.x;
  for (; i < n4; i += stride) {
    float4 v = reinterpret_cast<const float4*>(src)[i];
    ushort4 o = make_ushort4(f2bf(v.x), f2bf(v.y), f2bf(v.z), f2bf(v.w));
    reinterpret_cast<ushort4*>(dst)[i] = o;
  }
}

__global__ void zero_kernel(int* counts) {
  if (threadIdx.x < NEXP) counts[threadIdx.x] = 0;
}

// ---------------- gate: logits (fp64 accum), softmax, top2, bucket ----------------
__global__ __launch_bounds__(256) void gate_kernel(
    const float* __restrict__ tokens, const float* __restrict__ gate_w,
    int* __restrict__ list, float* __restrict__ listw, int* __restrict__ counts) {
  __shared__ float gw[NEXP * HID];   // 32 KB
  for (int i = threadIdx.x; i < NEXP * HID / 4; i += 256)
    reinterpret_cast<float4*>(gw)[i] = reinterpret_cast<const float4*>(gate_w)[i];
  __syncthreads();
  const int lane = threadIdx.x & 63;
  const int wave = threadIdx.x >> 6;
  const int gwid = blockIdx.x * 4 + wave;
  const int nw = gridDim.x * 4;
  for (int t = gwid; t < NTOK; t += nw) {
    const float4* xr = reinterpret_cast<const float4*>(tokens + (size_t)t * HID);
    double acc[NEXP];
#pragma unroll
    for (int e = 0; e < NEXP; e++) acc[e] = 0.0;
#pragma unroll
    for (int j = 0; j < 4; j++) {
      float4 x = xr[j * 64 + lane];
      int h0 = (j * 64 + lane) * 4;
#pragma unroll
      for (int e = 0; e < NEXP; e++) {
        acc[e] += (double)x.x * (double)gw[e * HID + h0]
                + (double)x.y * (double)gw[e * HID + h0 + 1]
                + (double)x.z * (double)gw[e * HID + h0 + 2]
                + (double)x.w * (double)gw[e * HID + h0 + 3];
      }
    }
#pragma unroll
    for (int e = 0; e < NEXP; e++) {
      double v = acc[e];
#pragma unroll
      for (int s = 32; s > 0; s >>= 1) v += __shfl_xor(v, s);
      acc[e] = v;
    }
    if (lane == 0) {
      int i1 = 0;
#pragma unroll
      for (int e = 1; e < NEXP; e++) if (acc[e] > acc[i1]) i1 = e;
      int i2 = (i1 == 0) ? 1 : 0;
#pragma unroll
      for (int e = 0; e < NEXP; e++) if (e != i1 && acc[e] > acc[i2]) i2 = e;
      double m = acc[i1];
      double s = 0.0;
#pragma unroll
      for (int e = 0; e < NEXP; e++) s += exp(acc[e] - m);
      float w1 = (float)(1.0 / s);
      float w2 = (float)(exp(acc[i2] - m) / s);
      int p1 = atomicAdd(&counts[i1], 1);
      if (p1 < CAP) { list[i1 * CAP + p1] = t;          listw[i1 * CAP + p1] = w1; }
      int p2 = atomicAdd(&counts[i2], 1);
      if (p2 < CAP) { list[i2 * CAP + p2] = t | 0x10000; listw[i2 * CAP + p2] = w2; }
    }
  }
}

// ---------------- mixed = contrib[0] + contrib[1] (bf16) ----------------
__global__ void mix_kernel(const ushort* __restrict__ contrib, ushort* __restrict__ mixed) {
  const int n8 = NTOK * HID / 8;
  int i = blockIdx.x * blockDim.x + threadIdx.x;
  int stride = gridDim.x * blockDim.x;
  const short8* c0 = reinterpret_cast<const short8*>(contrib);
  const short8* c1 = reinterpret_cast<const short8*>(contrib + (size_t)NTOK * HID);
  short8* mp = reinterpret_cast<short8*>(mixed);
  for (; i < n8; i += stride) {
    short8 a = c0[i], b = c1[i], o;
#pragma unroll
    for (int j = 0; j < 8; j++)
      o[j] = (short)f2bf(bf2f((ushort)a[j]) + bf2f((ushort)b[j]));
    mp[i] = o;
  }
}

// ---------------- GEMM: C[m,d] = sum_h A[m,h] * B[d,h]  (both row-major, bf16) ----------------
// EXPERT: A rows gathered via list; epilogue silu(x+b)*w -> contrib[slot][tok][d] (bf16)
// !EXPERT: plain rows; epilogue fp32 store to out
template <bool EXPERT>
__global__ __launch_bounds__(256) void gemm_kernel(
    const ushort* __restrict__ Ab, const ushort* __restrict__ Bb,
    const float* __restrict__ bias,
    const int* __restrict__ list, const float* __restrict__ listw,
    const int* __restrict__ counts,
    ushort* __restrict__ contrib, float* __restrict__ outp) {
  __shared__ ushort As[128 * 32];
  __shared__ ushort Bs[128 * 32];
  const int tid = threadIdx.x;
  const int lane = tid & 63;
  const int wave = tid >> 6;
  const int ct = blockIdx.x;
  const int rt = blockIdx.y;
  const int e = EXPERT ? blockIdx.z : 0;

  int count = NTOK;
  if constexpr (EXPERT) {
    count = counts[e];
    if (count > CAP) count = CAP;
    if (rt * 128 >= count) return;
  }

  // staging geometry: wave stages chunks cc0,cc0+1; chunk cc = rows [cc*16, cc*16+16)
  const int cc0 = wave * 2;
  const int rl0 = cc0 * 16 + (lane >> 2);
  const int rl1 = rl0 + 16;
  const int cOf = (lane & 3) * 8;   // ushort offset in 32-wide row (16B per lane)

  const ushort* srcA0;
  const ushort* srcA1;
  if constexpr (EXPERT) {
    int r0 = rt * 128 + rl0, r1 = rt * 128 + rl1;
    int t0 = (r0 < count) ? (list[e * CAP + r0] & 0xFFFF) : 0;
    int t1 = (r1 < count) ? (list[e * CAP + r1] & 0xFFFF) : 0;
    srcA0 = Ab + (size_t)t0 * HID + cOf;
    srcA1 = Ab + (size_t)t1 * HID + cOf;
  } else {
    srcA0 = Ab + (size_t)(rt * 128 + rl0) * HID + cOf;
    srcA1 = Ab + (size_t)(rt * 128 + rl1) * HID + cOf;
  }
  const ushort* Bbase = Bb + (EXPERT ? (size_t)e * HID * HID : 0);
  const ushort* srcB0 = Bbase + (size_t)(ct * 128 + rl0) * HID + cOf;
  const ushort* srcB1 = Bbase + (size_t)(ct * 128 + rl1) * HID + cOf;

  f32x4 acc[4][4];
#pragma unroll
  for (int m = 0; m < 4; m++)
#pragma unroll
    for (int n = 0; n < 4; n++) acc[m][n] = (f32x4){0.f, 0.f, 0.f, 0.f};

  const int wm = wave >> 1, wn = wave & 1;
  const int fr = lane & 15, fq = lane >> 4;

  for (int k0 = 0; k0 < HID; k0 += 32) {
    gl16(srcA0 + k0, &As[cc0 * 512]);
    gl16(srcA1 + k0, &As[cc0 * 512 + 512]);
    gl16(srcB0 + k0, &Bs[cc0 * 512]);
    gl16(srcB1 + k0, &Bs[cc0 * 512 + 512]);
    __syncthreads();   // drains vmcnt(0): LDS tiles ready
    bf16x8 av[4], bv[4];
#pragma unroll
    for (int m = 0; m < 4; m++)
      av[m] = *reinterpret_cast<const bf16x8*>(&As[(wm * 64 + m * 16 + fr) * 32 + fq * 8]);
#pragma unroll
    for (int n = 0; n < 4; n++)
      bv[n] = *reinterpret_cast<const bf16x8*>(&Bs[(wn * 64 + n * 16 + fr) * 32 + fq * 8]);
#pragma unroll
    for (int m = 0; m < 4; m++)
#pragma unroll
      for (int n = 0; n < 4; n++)
        acc[m][n] = __builtin_amdgcn_mfma_f32_16x16x32_bf16(av[m], bv[n], acc[m][n], 0, 0, 0);
    __syncthreads();   // reads done before next stage overwrites
  }

  const int colb = ct * 128 + wn * 64 + fr;
  if constexpr (EXPERT) {
    float bc[4];
#pragma unroll
    for (int n = 0; n < 4; n++) bc[n] = bias[e * HID + colb + n * 16];
#pragma unroll
    for (int m = 0; m < 4; m++) {
#pragma unroll
      for (int rr = 0; rr < 4; rr++) {
        int r = rt * 128 + wm * 64 + m * 16 + fq * 4 + rr;
        if (r < count) {
          int ent = list[e * CAP + r];
          int tok = ent & 0xFFFF;
          int slot = (ent >> 16) & 1;
          float wgt = listw[e * CAP + r];
          ushort* dst = contrib + ((size_t)slot * NTOK + tok) * HID;
#pragma unroll
          for (int n = 0; n < 4; n++) {
            float v = acc[m][n][rr] + bc[n];
            float sv = v / (1.0f + __expf(-v));
            dst[colb + n * 16] = f2bf(sv * wgt);
          }
        }
      }
    }
  } else {
#pragma unroll
    for (int m = 0; m < 4; m++)
#pragma unroll
      for (int rr = 0; rr < 4; rr++) {
        int r = rt * 128 + wm * 64 + m * 16 + fq * 4 + rr;
        float* dst = outp + (size_t)r * HID;
#pragma unroll
        for (int n = 0; n < 4; n++) dst[colb + n * 16] = acc[m][n][rr];
      }
  }
}

extern "C" void kernel_launch(void* const* d_in, const int* in_sizes, int n_in,
                              void* d_out, int out_size, void* d_ws, size_t ws_size,
                              hipStream_t stream) {
  const float* tokens    = (const float*)d_in[0];
  const float* gate_w    = (const float*)d_in[1];
  const float* expert_w  = (const float*)d_in[2];
  const float* expert_b  = (const float*)d_in[3];
  const float* combine_w = (const float*)d_in[4];
  float* outp = (float*)d_out;

  char* p = (char*)d_ws;
  ushort* Xb  = (ushort*)p; p += (size_t)NTOK * HID * 2;        // 33.5 MB (reused as mixed)
  ushort* Wxb = (ushort*)p; p += (size_t)NEXP * HID * HID * 2;  // 16.8 MB
  ushort* Wcb = (ushort*)p; p += (size_t)HID * HID * 2;         //  2.1 MB
  ushort* ctb = (ushort*)p; p += (size_t)2 * NTOK * HID * 2;    // 67.1 MB
  int*   list = (int*)p;    p += (size_t)NEXP * CAP * 4;
  float* lsw  = (float*)p;  p += (size_t)NEXP * CAP * 4;
  int*   cnts = (int*)p;    p += 256;
  ushort* mxb = Xb;  // Xb dead after expert GEMM; reuse for mixed

  cvt_kernel<<<2048, 256, 0, stream>>>(tokens, Xb, NTOK * HID / 4);
  cvt_kernel<<<1024, 256, 0, stream>>>(expert_w, Wxb, NEXP * HID * HID / 4);
  cvt_kernel<<<256, 256, 0, stream>>>(combine_w, Wcb, HID * HID / 4);
  zero_kernel<<<1, 64, 0, stream>>>(cnts);
  gate_kernel<<<512, 256, 0, stream>>>(tokens, gate_w, list, lsw, cnts);
  gemm_kernel<true><<<dim3(8, CAP / 128, NEXP), 256, 0, stream>>>(
      Xb, Wxb, expert_b, list, lsw, cnts, ctb, nullptr);
  mix_kernel<<<2048, 256, 0, stream>>>(ctb, mxb);
  gemm_kernel<false><<<dim3(8, NTOK / 128, 1), 256, 0, stream>>>(
      mxb, Wcb, nullptr, nullptr, nullptr, nullptr, nullptr, outp);
}

// Round 2
// 596.289 us; speedup vs baseline: 1.0355x; 1.0355x over previous
//
#include <hip/hip_runtime.h>
#include <stdint.h>

#define HID 1024
#define NEXP 8
#define NTOK 16384
#define CAP 8192

typedef __attribute__((ext_vector_type(8))) __bf16 bf16x8;
typedef __attribute__((ext_vector_type(8))) short short8;
typedef __attribute__((ext_vector_type(4))) float f32x4;

__device__ __forceinline__ ushort f2bf(float f) {
  uint32_t u = __builtin_bit_cast(uint32_t, f);
  u += 0x7FFF + ((u >> 16) & 1);          // round-to-nearest-even
  return (ushort)(u >> 16);
}
__device__ __forceinline__ float bf2f(ushort u) {
  return __builtin_bit_cast(float, (uint32_t)u << 16);
}

__device__ __forceinline__ void gl16(const void* g, void* l) {
  __builtin_amdgcn_global_load_lds((__attribute__((address_space(1))) void*)(g),
                                   (__attribute__((address_space(3))) void*)(l),
                                   16, 0, 0);
}

// ---------------- fp32 -> bf16 conversion (weights only now) ----------------
__global__ void cvt_kernel(const float* __restrict__ src, ushort* __restrict__ dst, int n4) {
  int i = blockIdx.x * blockDim.x + threadIdx.x;
  int stride = gridDim.x * blockDim.x;
  for (; i < n4; i += stride) {
    float4 v = reinterpret_cast<const float4*>(src)[i];
    ushort4 o = make_ushort4(f2bf(v.x), f2bf(v.y), f2bf(v.z), f2bf(v.w));
    reinterpret_cast<ushort4*>(dst)[i] = o;
  }
}

__global__ void zero_kernel(int* counts) {
  if (threadIdx.x < NEXP) counts[threadIdx.x] = 0;
}

// ---------------- gate: fp32 logits + fused tokens->bf16 cvt ----------------
// Per wave: one token at a time. Lane holds 16 consecutive floats (4 float4s).
// gate_w slices live in registers (lane-fixed across tokens).
__global__ __launch_bounds__(256) void gate_kernel(
    const float* __restrict__ tokens, const float* __restrict__ gate_w,
    ushort* __restrict__ Xb,
    int* __restrict__ list, float* __restrict__ listw, int* __restrict__ counts) {
  const int lane = threadIdx.x & 63;
  const int wave = threadIdx.x >> 6;
  // preload gate weights: rg[e][j] matches x chunk at float4 index j*64+lane
  float4 rg[NEXP][4];
#pragma unroll
  for (int e = 0; e < NEXP; e++)
#pragma unroll
    for (int j = 0; j < 4; j++)
      rg[e][j] = reinterpret_cast<const float4*>(gate_w)[e * 256 + j * 64 + lane];

  const int gwid = blockIdx.x * 4 + wave;
  const int nw = gridDim.x * 4;
  for (int t = gwid; t < NTOK; t += nw) {
    const float4* xr = reinterpret_cast<const float4*>(tokens + (size_t)t * HID);
    float acc[NEXP];
#pragma unroll
    for (int e = 0; e < NEXP; e++) acc[e] = 0.f;
    ushort4 xs[4];
#pragma unroll
    for (int j = 0; j < 4; j++) {
      float4 x = xr[j * 64 + lane];
      xs[j] = make_ushort4(f2bf(x.x), f2bf(x.y), f2bf(x.z), f2bf(x.w));
#pragma unroll
      for (int e = 0; e < NEXP; e++) {
        acc[e] = fmaf(x.x, rg[e][j].x,
                 fmaf(x.y, rg[e][j].y,
                 fmaf(x.z, rg[e][j].z,
                 fmaf(x.w, rg[e][j].w, acc[e]))));
      }
    }
    // fused tokens -> bf16 store (coalesced 8B/lane)
    ushort4* xo = reinterpret_cast<ushort4*>(Xb + (size_t)t * HID);
#pragma unroll
    for (int j = 0; j < 4; j++) xo[j * 64 + lane] = xs[j];
    // full butterfly: every lane ends with all 8 logits (compile-time indexed)
#pragma unroll
    for (int e = 0; e < NEXP; e++) {
#pragma unroll
      for (int s = 32; s > 0; s >>= 1) acc[e] += __shfl_xor(acc[e], s);
    }
    // redundant-uniform top2 + softmax on all lanes; lane 0 commits
    int i1 = 0;
#pragma unroll
    for (int e = 1; e < NEXP; e++) if (acc[e] > acc[i1]) i1 = e;
    int i2 = (i1 == 0) ? 1 : 0;
#pragma unroll
    for (int e = 0; e < NEXP; e++) if (e != i1 && acc[e] > acc[i2]) i2 = e;
    float m = acc[i1];
    float s = 0.f;
#pragma unroll
    for (int e = 0; e < NEXP; e++) s += __expf(acc[e] - m);
    float w1 = 1.f / s;
    float w2 = __expf(acc[i2] - m) / s;
    if (lane == 0) {
      int p1 = atomicAdd(&counts[i1], 1);
      if (p1 < CAP) { list[i1 * CAP + p1] = t;           listw[i1 * CAP + p1] = w1; }
      int p2 = atomicAdd(&counts[i2], 1);
      if (p2 < CAP) { list[i2 * CAP + p2] = t | 0x10000; listw[i2 * CAP + p2] = w2; }
    }
  }
}

// ---------------- mixed = contrib[0] + contrib[1] (bf16) ----------------
__global__ void mix_kernel(const ushort* __restrict__ contrib, ushort* __restrict__ mixed) {
  const int n8 = NTOK * HID / 8;
  int i = blockIdx.x * blockDim.x + threadIdx.x;
  int stride = gridDim.x * blockDim.x;
  const short8* c0 = reinterpret_cast<const short8*>(contrib);
  const short8* c1 = reinterpret_cast<const short8*>(contrib + (size_t)NTOK * HID);
  short8* mp = reinterpret_cast<short8*>(mixed);
  for (; i < n8; i += stride) {
    short8 a = c0[i], b = c1[i], o;
#pragma unroll
    for (int j = 0; j < 8; j++)
      o[j] = (short)f2bf(bf2f((ushort)a[j]) + bf2f((ushort)b[j]));
    mp[i] = o;
  }
}

// ---------------- GEMM: C[m,d] = sum_h A[m,h] * B[d,h]  (both row-major, bf16) ----------------
// EXPERT: A rows gathered via list; epilogue silu(x+b)*w -> contrib[slot][tok][d] (bf16)
// !EXPERT: plain rows; epilogue fp32 store to out
template <bool EXPERT>
__global__ __launch_bounds__(256) void gemm_kernel(
    const ushort* __restrict__ Ab, const ushort* __restrict__ Bb,
    const float* __restrict__ bias,
    const int* __restrict__ list, const float* __restrict__ listw,
    const int* __restrict__ counts,
    ushort* __restrict__ contrib, float* __restrict__ outp) {
  __shared__ ushort As[128 * 32];
  __shared__ ushort Bs[128 * 32];
  const int tid = threadIdx.x;
  const int lane = tid & 63;
  const int wave = tid >> 6;
  const int ct = blockIdx.x;
  const int rt = blockIdx.y;
  const int e = EXPERT ? blockIdx.z : 0;

  int count = NTOK;
  if constexpr (EXPERT) {
    count = counts[e];
    if (count > CAP) count = CAP;
    if (rt * 128 >= count) return;
  }

  // staging geometry: wave stages chunks cc0,cc0+1; chunk cc = rows [cc*16, cc*16+16)
  const int cc0 = wave * 2;
  const int rl0 = cc0 * 16 + (lane >> 2);
  const int rl1 = rl0 + 16;
  const int cOf = (lane & 3) * 8;   // ushort offset in 32-wide row (16B per lane)

  const ushort* srcA0;
  const ushort* srcA1;
  if constexpr (EXPERT) {
    int r0 = rt * 128 + rl0, r1 = rt * 128 + rl1;
    int t0 = (r0 < count) ? (list[e * CAP + r0] & 0xFFFF) : 0;
    int t1 = (r1 < count) ? (list[e * CAP + r1] & 0xFFFF) : 0;
    srcA0 = Ab + (size_t)t0 * HID + cOf;
    srcA1 = Ab + (size_t)t1 * HID + cOf;
  } else {
    srcA0 = Ab + (size_t)(rt * 128 + rl0) * HID + cOf;
    srcA1 = Ab + (size_t)(rt * 128 + rl1) * HID + cOf;
  }
  const ushort* Bbase = Bb + (EXPERT ? (size_t)e * HID * HID : 0);
  const ushort* srcB0 = Bbase + (size_t)(ct * 128 + rl0) * HID + cOf;
  const ushort* srcB1 = Bbase + (size_t)(ct * 128 + rl1) * HID + cOf;

  f32x4 acc[4][4];
#pragma unroll
  for (int m = 0; m < 4; m++)
#pragma unroll
    for (int n = 0; n < 4; n++) acc[m][n] = (f32x4){0.f, 0.f, 0.f, 0.f};

  const int wm = wave >> 1, wn = wave & 1;
  const int fr = lane & 15, fq = lane >> 4;

  for (int k0 = 0; k0 < HID; k0 += 32) {
    gl16(srcA0 + k0, &As[cc0 * 512]);
    gl16(srcA1 + k0, &As[cc0 * 512 + 512]);
    gl16(srcB0 + k0, &Bs[cc0 * 512]);
    gl16(srcB1 + k0, &Bs[cc0 * 512 + 512]);
    __syncthreads();   // drains vmcnt(0): LDS tiles ready
    bf16x8 av[4], bv[4];
#pragma unroll
    for (int m = 0; m < 4; m++)
      av[m] = *reinterpret_cast<const bf16x8*>(&As[(wm * 64 + m * 16 + fr) * 32 + fq * 8]);
#pragma unroll
    for (int n = 0; n < 4; n++)
      bv[n] = *reinterpret_cast<const bf16x8*>(&Bs[(wn * 64 + n * 16 + fr) * 32 + fq * 8]);
#pragma unroll
    for (int m = 0; m < 4; m++)
#pragma unroll
      for (int n = 0; n < 4; n++)
        acc[m][n] = __builtin_amdgcn_mfma_f32_16x16x32_bf16(av[m], bv[n], acc[m][n], 0, 0, 0);
    __syncthreads();   // reads done before next stage overwrites
  }

  const int colb = ct * 128 + wn * 64 + fr;
  if constexpr (EXPERT) {
    float bc[4];
#pragma unroll
    for (int n = 0; n < 4; n++) bc[n] = bias[e * HID + colb + n * 16];
#pragma unroll
    for (int m = 0; m < 4; m++) {
#pragma unroll
      for (int rr = 0; rr < 4; rr++) {
        int r = rt * 128 + wm * 64 + m * 16 + fq * 4 + rr;
        if (r < count) {
          int ent = list[e * CAP + r];
          int tok = ent & 0xFFFF;
          int slot = (ent >> 16) & 1;
          float wgt = listw[e * CAP + r];
          ushort* dst = contrib + ((size_t)slot * NTOK + tok) * HID;
#pragma unroll
          for (int n = 0; n < 4; n++) {
            float v = acc[m][n][rr] + bc[n];
            float sv = v / (1.0f + __expf(-v));
            dst[colb + n * 16] = f2bf(sv * wgt);
          }
        }
      }
    }
  } else {
#pragma unroll
    for (int m = 0; m < 4; m++)
#pragma unroll
      for (int rr = 0; rr < 4; rr++) {
        int r = rt * 128 + wm * 64 + m * 16 + fq * 4 + rr;
        float* dst = outp + (size_t)r * HID;
#pragma unroll
        for (int n = 0; n < 4; n++) dst[colb + n * 16] = acc[m][n][rr];
      }
  }
}

extern "C" void kernel_launch(void* const* d_in, const int* in_sizes, int n_in,
                              void* d_out, int out_size, void* d_ws, size_t ws_size,
                              hipStream_t stream) {
  const float* tokens    = (const float*)d_in[0];
  const float* gate_w    = (const float*)d_in[1];
  const float* expert_w  = (const float*)d_in[2];
  const float* expert_b  = (const float*)d_in[3];
  const float* combine_w = (const float*)d_in[4];
  float* outp = (float*)d_out;

  char* p = (char*)d_ws;
  ushort* Xb  = (ushort*)p; p += (size_t)NTOK * HID * 2;        // 33.5 MB (reused as mixed)
  ushort* Wxb = (ushort*)p; p += (size_t)NEXP * HID * HID * 2;  // 16.8 MB
  ushort* Wcb = (ushort*)p; p += (size_t)HID * HID * 2;         //  2.1 MB
  ushort* ctb = (ushort*)p; p += (size_t)2 * NTOK * HID * 2;    // 67.1 MB
  int*   list = (int*)p;    p += (size_t)NEXP * CAP * 4;
  float* lsw  = (float*)p;  p += (size_t)NEXP * CAP * 4;
  int*   cnts = (int*)p;    p += 256;
  ushort* mxb = Xb;  // Xb dead after expert GEMM; reuse for mixed

  zero_kernel<<<1, 64, 0, stream>>>(cnts);
  gate_kernel<<<1024, 256, 0, stream>>>(tokens, gate_w, Xb, list, lsw, cnts);
  cvt_kernel<<<1024, 256, 0, stream>>>(expert_w, Wxb, NEXP * HID * HID / 4);
  cvt_kernel<<<256, 256, 0, stream>>>(combine_w, Wcb, HID * HID / 4);
  gemm_kernel<true><<<dim3(8, CAP / 128, NEXP), 256, 0, stream>>>(
      Xb, Wxb, expert_b, list, lsw, cnts, ctb, nullptr);
  mix_kernel<<<2048, 256, 0, stream>>>(ctb, mxb);
  gemm_kernel<false><<<dim3(8, NTOK / 128, 1), 256, 0, stream>>>(
      mxb, Wcb, nullptr, nullptr, nullptr, nullptr, nullptr, outp);
}

// Round 3
// 256.135 us; speedup vs baseline: 2.4107x; 2.3280x over previous
//
#include <hip/hip_runtime.h>
#include <stdint.h>

#define HID 1024
#define NEXP 8
#define NTOK 16384
#define CAP 8192

typedef __attribute__((ext_vector_type(8))) __bf16 bf16x8;
typedef __attribute__((ext_vector_type(8))) short short8;
typedef __attribute__((ext_vector_type(4))) float f32x4;

__device__ __forceinline__ ushort f2bf(float f) {
  uint32_t u = __builtin_bit_cast(uint32_t, f);
  u += 0x7FFF + ((u >> 16) & 1);          // round-to-nearest-even
  return (ushort)(u >> 16);
}
__device__ __forceinline__ float bf2f(ushort u) {
  return __builtin_bit_cast(float, (uint32_t)u << 16);
}

__device__ __forceinline__ void gl16(const void* g, void* l) {
  __builtin_amdgcn_global_load_lds((__attribute__((address_space(1))) void*)(g),
                                   (__attribute__((address_space(3))) void*)(l),
                                   16, 0, 0);
}

// ---------------- fp32 -> bf16 conversion (weights only) ----------------
__global__ void cvt_kernel(const float* __restrict__ src, ushort* __restrict__ dst, int n4) {
  int i = blockIdx.x * blockDim.x + threadIdx.x;
  int stride = gridDim.x * blockDim.x;
  for (; i < n4; i += stride) {
    float4 v = reinterpret_cast<const float4*>(src)[i];
    ushort4 o = make_ushort4(f2bf(v.x), f2bf(v.y), f2bf(v.z), f2bf(v.w));
    reinterpret_cast<ushort4*>(dst)[i] = o;
  }
}

__global__ void zero_kernel(int* counts) {
  if (threadIdx.x < NEXP) counts[threadIdx.x] = 0;
}

// ---------------- gate: fp32 logits + fused tokens->bf16 cvt; NO atomics ----------------
__global__ __launch_bounds__(256) void gate_kernel(
    const float* __restrict__ tokens, const float* __restrict__ gate_w,
    ushort* __restrict__ Xb,
    uint32_t* __restrict__ tinfo, float2* __restrict__ tw) {
  const int lane = threadIdx.x & 63;
  const int wave = threadIdx.x >> 6;
  float4 rg[NEXP][4];
#pragma unroll
  for (int e = 0; e < NEXP; e++)
#pragma unroll
    for (int j = 0; j < 4; j++)
      rg[e][j] = reinterpret_cast<const float4*>(gate_w)[e * 256 + j * 64 + lane];

  const int gwid = blockIdx.x * 4 + wave;
  const int nw = gridDim.x * 4;
  for (int t = gwid; t < NTOK; t += nw) {
    const float4* xr = reinterpret_cast<const float4*>(tokens + (size_t)t * HID);
    float acc[NEXP];
#pragma unroll
    for (int e = 0; e < NEXP; e++) acc[e] = 0.f;
    ushort4 xs[4];
#pragma unroll
    for (int j = 0; j < 4; j++) {
      float4 x = xr[j * 64 + lane];
      xs[j] = make_ushort4(f2bf(x.x), f2bf(x.y), f2bf(x.z), f2bf(x.w));
#pragma unroll
      for (int e = 0; e < NEXP; e++) {
        acc[e] = fmaf(x.x, rg[e][j].x,
                 fmaf(x.y, rg[e][j].y,
                 fmaf(x.z, rg[e][j].z,
                 fmaf(x.w, rg[e][j].w, acc[e]))));
      }
    }
    ushort4* xo = reinterpret_cast<ushort4*>(Xb + (size_t)t * HID);
#pragma unroll
    for (int j = 0; j < 4; j++) xo[j * 64 + lane] = xs[j];
#pragma unroll
    for (int e = 0; e < NEXP; e++) {
#pragma unroll
      for (int s = 32; s > 0; s >>= 1) acc[e] += __shfl_xor(acc[e], s);
    }
    // redundant-uniform top2 + softmax (identical FMA/order to validated r2)
    int i1 = 0;
#pragma unroll
    for (int e = 1; e < NEXP; e++) if (acc[e] > acc[i1]) i1 = e;
    int i2 = (i1 == 0) ? 1 : 0;
#pragma unroll
    for (int e = 0; e < NEXP; e++) if (e != i1 && acc[e] > acc[i2]) i2 = e;
    float m = acc[i1];
    float s = 0.f;
#pragma unroll
    for (int e = 0; e < NEXP; e++) s += __expf(acc[e] - m);
    float w1 = 1.f / s;
    float w2 = __expf(acc[i2] - m) / s;
    if (lane == 0) {
      tinfo[t] = (uint32_t)i1 | ((uint32_t)i2 << 8);
      tw[t] = make_float2(w1, w2);
    }
  }
}

// ---------------- scatter: block-aggregated list build (512 global atomics total) ----------------
__global__ __launch_bounds__(256) void scatter_kernel(
    const uint32_t* __restrict__ tinfo, const float2* __restrict__ tw,
    int* __restrict__ list, float* __restrict__ listw, int* __restrict__ counts) {
  __shared__ int lhist[NEXP];
  __shared__ int gbase[NEXP];
  const int tid = threadIdx.x;
  if (tid < NEXP) lhist[tid] = 0;
  __syncthreads();
  const int t = blockIdx.x * 256 + tid;
  uint32_t info = tinfo[t];
  int i1 = info & 0xFF, i2 = (info >> 8) & 0xFF;
  float2 w = tw[t];
  int lr1 = atomicAdd(&lhist[i1], 1);
  int lr2 = atomicAdd(&lhist[i2], 1);
  __syncthreads();
  if (tid < NEXP) gbase[tid] = atomicAdd(&counts[tid], lhist[tid]);
  __syncthreads();
  int p1 = gbase[i1] + lr1;
  if (p1 < CAP) { list[i1 * CAP + p1] = t;           listw[i1 * CAP + p1] = w.x; }
  int p2 = gbase[i2] + lr2;
  if (p2 < CAP) { list[i2 * CAP + p2] = t | 0x10000; listw[i2 * CAP + p2] = w.y; }
}

// ---------------- mixed = contrib[0] + contrib[1] (bf16) ----------------
__global__ void mix_kernel(const ushort* __restrict__ contrib, ushort* __restrict__ mixed) {
  const int n8 = NTOK * HID / 8;
  int i = blockIdx.x * blockDim.x + threadIdx.x;
  int stride = gridDim.x * blockDim.x;
  const short8* c0 = reinterpret_cast<const short8*>(contrib);
  const short8* c1 = reinterpret_cast<const short8*>(contrib + (size_t)NTOK * HID);
  short8* mp = reinterpret_cast<short8*>(mixed);
  for (; i < n8; i += stride) {
    short8 a = c0[i], b = c1[i], o;
#pragma unroll
    for (int j = 0; j < 8; j++)
      o[j] = (short)f2bf(bf2f((ushort)a[j]) + bf2f((ushort)b[j]));
    mp[i] = o;
  }
}

// ---------------- GEMM: C[m,d] = sum_h A[m,h] * B[d,h]  (both row-major, bf16) ----------------
template <bool EXPERT>
__global__ __launch_bounds__(256) void gemm_kernel(
    const ushort* __restrict__ Ab, const ushort* __restrict__ Bb,
    const float* __restrict__ bias,
    const int* __restrict__ list, const float* __restrict__ listw,
    const int* __restrict__ counts,
    ushort* __restrict__ contrib, float* __restrict__ outp) {
  __shared__ ushort As[128 * 32];
  __shared__ ushort Bs[128 * 32];
  const int tid = threadIdx.x;
  const int lane = tid & 63;
  const int wave = tid >> 6;
  const int ct = blockIdx.x;
  const int rt = blockIdx.y;
  const int e = EXPERT ? blockIdx.z : 0;

  int count = NTOK;
  if constexpr (EXPERT) {
    count = counts[e];
    if (count > CAP) count = CAP;
    if (rt * 128 >= count) return;
  }

  const int cc0 = wave * 2;
  const int rl0 = cc0 * 16 + (lane >> 2);
  const int rl1 = rl0 + 16;
  const int cOf = (lane & 3) * 8;

  const ushort* srcA0;
  const ushort* srcA1;
  if constexpr (EXPERT) {
    int r0 = rt * 128 + rl0, r1 = rt * 128 + rl1;
    int t0 = (r0 < count) ? (list[e * CAP + r0] & 0xFFFF) : 0;
    int t1 = (r1 < count) ? (list[e * CAP + r1] & 0xFFFF) : 0;
    srcA0 = Ab + (size_t)t0 * HID + cOf;
    srcA1 = Ab + (size_t)t1 * HID + cOf;
  } else {
    srcA0 = Ab + (size_t)(rt * 128 + rl0) * HID + cOf;
    srcA1 = Ab + (size_t)(rt * 128 + rl1) * HID + cOf;
  }
  const ushort* Bbase = Bb + (EXPERT ? (size_t)e * HID * HID : 0);
  const ushort* srcB0 = Bbase + (size_t)(ct * 128 + rl0) * HID + cOf;
  const ushort* srcB1 = Bbase + (size_t)(ct * 128 + rl1) * HID + cOf;

  f32x4 acc[4][4];
#pragma unroll
  for (int m = 0; m < 4; m++)
#pragma unroll
    for (int n = 0; n < 4; n++) acc[m][n] = (f32x4){0.f, 0.f, 0.f, 0.f};

  const int wm = wave >> 1, wn = wave & 1;
  const int fr = lane & 15, fq = lane >> 4;

  for (int k0 = 0; k0 < HID; k0 += 32) {
    gl16(srcA0 + k0, &As[cc0 * 512]);
    gl16(srcA1 + k0, &As[cc0 * 512 + 512]);
    gl16(srcB0 + k0, &Bs[cc0 * 512]);
    gl16(srcB1 + k0, &Bs[cc0 * 512 + 512]);
    __syncthreads();
    bf16x8 av[4], bv[4];
#pragma unroll
    for (int m = 0; m < 4; m++)
      av[m] = *reinterpret_cast<const bf16x8*>(&As[(wm * 64 + m * 16 + fr) * 32 + fq * 8]);
#pragma unroll
    for (int n = 0; n < 4; n++)
      bv[n] = *reinterpret_cast<const bf16x8*>(&Bs[(wn * 64 + n * 16 + fr) * 32 + fq * 8]);
#pragma unroll
    for (int m = 0; m < 4; m++)
#pragma unroll
      for (int n = 0; n < 4; n++)
        acc[m][n] = __builtin_amdgcn_mfma_f32_16x16x32_bf16(av[m], bv[n], acc[m][n], 0, 0, 0);
    __syncthreads();
  }

  const int colb = ct * 128 + wn * 64 + fr;
  if constexpr (EXPERT) {
    float bc[4];
#pragma unroll
    for (int n = 0; n < 4; n++) bc[n] = bias[e * HID + colb + n * 16];
#pragma unroll
    for (int m = 0; m < 4; m++) {
#pragma unroll
      for (int rr = 0; rr < 4; rr++) {
        int r = rt * 128 + wm * 64 + m * 16 + fq * 4 + rr;
        if (r < count) {
          int ent = list[e * CAP + r];
          int tok = ent & 0xFFFF;
          int slot = (ent >> 16) & 1;
          float wgt = listw[e * CAP + r];
          ushort* dst = contrib + ((size_t)slot * NTOK + tok) * HID;
#pragma unroll
          for (int n = 0; n < 4; n++) {
            float v = acc[m][n][rr] + bc[n];
            float sv = v / (1.0f + __expf(-v));
            dst[colb + n * 16] = f2bf(sv * wgt);
          }
        }
      }
    }
  } else {
#pragma unroll
    for (int m = 0; m < 4; m++)
#pragma unroll
      for (int rr = 0; rr < 4; rr++) {
        int r = rt * 128 + wm * 64 + m * 16 + fq * 4 + rr;
        float* dst = outp + (size_t)r * HID;
#pragma unroll
        for (int n = 0; n < 4; n++) dst[colb + n * 16] = acc[m][n][rr];
      }
  }
}

extern "C" void kernel_launch(void* const* d_in, const int* in_sizes, int n_in,
                              void* d_out, int out_size, void* d_ws, size_t ws_size,
                              hipStream_t stream) {
  const float* tokens    = (const float*)d_in[0];
  const float* gate_w    = (const float*)d_in[1];
  const float* expert_w  = (const float*)d_in[2];
  const float* expert_b  = (const float*)d_in[3];
  const float* combine_w = (const float*)d_in[4];
  float* outp = (float*)d_out;

  char* p = (char*)d_ws;
  ushort* Xb  = (ushort*)p; p += (size_t)NTOK * HID * 2;        // 33.5 MB (reused as mixed)
  ushort* Wxb = (ushort*)p; p += (size_t)NEXP * HID * HID * 2;  // 16.8 MB
  ushort* Wcb = (ushort*)p; p += (size_t)HID * HID * 2;         //  2.1 MB
  ushort* ctb = (ushort*)p; p += (size_t)2 * NTOK * HID * 2;    // 67.1 MB
  int*   list = (int*)p;    p += (size_t)NEXP * CAP * 4;
  float* lsw  = (float*)p;  p += (size_t)NEXP * CAP * 4;
  int*   cnts = (int*)p;    p += 256;
  uint32_t* tinfo = (uint32_t*)p; p += (size_t)NTOK * 4;
  float2*   twp   = (float2*)p;   p += (size_t)NTOK * 8;
  ushort* mxb = Xb;  // Xb dead after expert GEMM; reuse for mixed

  zero_kernel<<<1, 64, 0, stream>>>(cnts);
  gate_kernel<<<2048, 256, 0, stream>>>(tokens, gate_w, Xb, tinfo, twp);
  cvt_kernel<<<1024, 256, 0, stream>>>(expert_w, Wxb, NEXP * HID * HID / 4);
  cvt_kernel<<<256, 256, 0, stream>>>(combine_w, Wcb, HID * HID / 4);
  scatter_kernel<<<64, 256, 0, stream>>>(tinfo, twp, list, lsw, cnts);
  gemm_kernel<true><<<dim3(8, CAP / 128, NEXP), 256, 0, stream>>>(
      Xb, Wxb, expert_b, list, lsw, cnts, ctb, nullptr);
  mix_kernel<<<2048, 256, 0, stream>>>(ctb, mxb);
  gemm_kernel<false><<<dim3(8, NTOK / 128, 1), 256, 0, stream>>>(
      mxb, Wcb, nullptr, nullptr, nullptr, nullptr, nullptr, outp);
}

// Round 4
// 246.975 us; speedup vs baseline: 2.5001x; 1.0371x over previous
//
#include <hip/hip_runtime.h>
#include <stdint.h>

#define HID 1024
#define NEXP 8
#define NTOK 16384
#define CAP 8192

typedef __attribute__((ext_vector_type(8))) __bf16 bf16x8;
typedef __attribute__((ext_vector_type(8))) short short8;
typedef __attribute__((ext_vector_type(4))) float f32x4;

__device__ __forceinline__ ushort f2bf(float f) {
  uint32_t u = __builtin_bit_cast(uint32_t, f);
  u += 0x7FFF + ((u >> 16) & 1);          // round-to-nearest-even
  return (ushort)(u >> 16);
}
__device__ __forceinline__ float bf2f(ushort u) {
  return __builtin_bit_cast(float, (uint32_t)u << 16);
}

__device__ __forceinline__ void gl16(const void* g, void* l) {
  __builtin_amdgcn_global_load_lds((__attribute__((address_space(1))) void*)(g),
                                   (__attribute__((address_space(3))) void*)(l),
                                   16, 0, 0);
}

// ---------------- fp32 -> bf16 conversion (weights only) ----------------
__global__ void cvt_kernel(const float* __restrict__ src, ushort* __restrict__ dst, int n4) {
  int i = blockIdx.x * blockDim.x + threadIdx.x;
  int stride = gridDim.x * blockDim.x;
  for (; i < n4; i += stride) {
    float4 v = reinterpret_cast<const float4*>(src)[i];
    ushort4 o = make_ushort4(f2bf(v.x), f2bf(v.y), f2bf(v.z), f2bf(v.w));
    reinterpret_cast<ushort4*>(dst)[i] = o;
  }
}

__global__ void zero_kernel(int* counts) {
  if (threadIdx.x < NEXP) counts[threadIdx.x] = 0;
}

// ---------------- gate: fp32 logits + fused tokens->bf16 cvt; NO atomics ----------------
__global__ __launch_bounds__(256) void gate_kernel(
    const float* __restrict__ tokens, const float* __restrict__ gate_w,
    ushort* __restrict__ Xb,
    uint32_t* __restrict__ tinfo, float2* __restrict__ tw) {
  const int lane = threadIdx.x & 63;
  const int wave = threadIdx.x >> 6;
  float4 rg[NEXP][4];
#pragma unroll
  for (int e = 0; e < NEXP; e++)
#pragma unroll
    for (int j = 0; j < 4; j++)
      rg[e][j] = reinterpret_cast<const float4*>(gate_w)[e * 256 + j * 64 + lane];

  const int gwid = blockIdx.x * 4 + wave;
  const int nw = gridDim.x * 4;
  for (int t = gwid; t < NTOK; t += nw) {
    const float4* xr = reinterpret_cast<const float4*>(tokens + (size_t)t * HID);
    float acc[NEXP];
#pragma unroll
    for (int e = 0; e < NEXP; e++) acc[e] = 0.f;
    ushort4 xs[4];
#pragma unroll
    for (int j = 0; j < 4; j++) {
      float4 x = xr[j * 64 + lane];
      xs[j] = make_ushort4(f2bf(x.x), f2bf(x.y), f2bf(x.z), f2bf(x.w));
#pragma unroll
      for (int e = 0; e < NEXP; e++) {
        acc[e] = fmaf(x.x, rg[e][j].x,
                 fmaf(x.y, rg[e][j].y,
                 fmaf(x.z, rg[e][j].z,
                 fmaf(x.w, rg[e][j].w, acc[e]))));
      }
    }
    ushort4* xo = reinterpret_cast<ushort4*>(Xb + (size_t)t * HID);
#pragma unroll
    for (int j = 0; j < 4; j++) xo[j * 64 + lane] = xs[j];
#pragma unroll
    for (int e = 0; e < NEXP; e++) {
#pragma unroll
      for (int s = 32; s > 0; s >>= 1) acc[e] += __shfl_xor(acc[e], s);
    }
    int i1 = 0;
#pragma unroll
    for (int e = 1; e < NEXP; e++) if (acc[e] > acc[i1]) i1 = e;
    int i2 = (i1 == 0) ? 1 : 0;
#pragma unroll
    for (int e = 0; e < NEXP; e++) if (e != i1 && acc[e] > acc[i2]) i2 = e;
    float m = acc[i1];
    float s = 0.f;
#pragma unroll
    for (int e = 0; e < NEXP; e++) s += __expf(acc[e] - m);
    float w1 = 1.f / s;
    float w2 = __expf(acc[i2] - m) / s;
    if (lane == 0) {
      tinfo[t] = (uint32_t)i1 | ((uint32_t)i2 << 8);
      tw[t] = make_float2(w1, w2);
    }
  }
}

// ---------------- scatter: block-aggregated list build ----------------
__global__ __launch_bounds__(256) void scatter_kernel(
    const uint32_t* __restrict__ tinfo, const float2* __restrict__ tw,
    int* __restrict__ list, float* __restrict__ listw, int* __restrict__ counts) {
  __shared__ int lhist[NEXP];
  __shared__ int gbase[NEXP];
  const int tid = threadIdx.x;
  if (tid < NEXP) lhist[tid] = 0;
  __syncthreads();
  const int t = blockIdx.x * 256 + tid;
  uint32_t info = tinfo[t];
  int i1 = info & 0xFF, i2 = (info >> 8) & 0xFF;
  float2 w = tw[t];
  int lr1 = atomicAdd(&lhist[i1], 1);
  int lr2 = atomicAdd(&lhist[i2], 1);
  __syncthreads();
  if (tid < NEXP) gbase[tid] = atomicAdd(&counts[tid], lhist[tid]);
  __syncthreads();
  int p1 = gbase[i1] + lr1;
  if (p1 < CAP) { list[i1 * CAP + p1] = t;           listw[i1 * CAP + p1] = w.x; }
  int p2 = gbase[i2] + lr2;
  if (p2 < CAP) { list[i2 * CAP + p2] = t | 0x10000; listw[i2 * CAP + p2] = w.y; }
}

// ---------------- expert GEMM: counted-vmcnt 2-deep pipeline ----------------
// LDS layout: row-major [128][32] ushorts, content(slot s) = global chunk (s ^ rowswz)
// achieved by pre-swizzled SOURCE col with linear gl16 dest (rule #21).
__global__ __launch_bounds__(256) void egemm_kernel(
    const ushort* __restrict__ Ab, const ushort* __restrict__ Bb,
    const float* __restrict__ bias,
    const int* __restrict__ list, const float* __restrict__ listw,
    const int* __restrict__ counts, ushort* __restrict__ contrib) {
  __shared__ ushort As[2][128 * 32];
  __shared__ ushort Bs[2][128 * 32];
  const int tid = threadIdx.x, lane = tid & 63, wave = tid >> 6;
  // bijective XCD swizzle: all 8 ct of a (e,rt) group share p%8 (one XCD)
  const int p = blockIdx.x;
  const int cx = p & 7, q = p >> 3, ct = q & 7, g = ((q >> 3) << 3) | cx;
  const int e = g >> 6, rt = g & 63;
  int count = counts[e]; if (count > CAP) count = CAP;
  if (rt * 128 >= count) return;

  const int cc0 = wave * 2;
  const int rl0 = cc0 * 16 + (lane >> 2);
  const int rl1 = rl0 + 16;
  const int swz8 = (((lane & 3) ^ ((lane >> 3) & 3))) * 8;  // pre-swizzled src col (ushorts)

  int r0 = rt * 128 + rl0, r1 = rt * 128 + rl1;
  int t0 = (r0 < count) ? (list[e * CAP + r0] & 0xFFFF) : 0;
  int t1 = (r1 < count) ? (list[e * CAP + r1] & 0xFFFF) : 0;
  const ushort* srcA0 = Ab + (size_t)t0 * HID + swz8;
  const ushort* srcA1 = Ab + (size_t)t1 * HID + swz8;
  const ushort* Bbase = Bb + (size_t)e * HID * HID;
  const ushort* srcB0 = Bbase + (size_t)(ct * 128 + rl0) * HID + swz8;
  const ushort* srcB1 = Bbase + (size_t)(ct * 128 + rl1) * HID + swz8;

  f32x4 acc[4][4];
#pragma unroll
  for (int m = 0; m < 4; m++)
#pragma unroll
    for (int n = 0; n < 4; n++) acc[m][n] = (f32x4){0.f, 0.f, 0.f, 0.f};

  const int wm = wave >> 1, wn = wave & 1;
  const int fr = lane & 15, fq = lane >> 4;
  const int sa = (fq ^ ((fr >> 1) & 3)) * 8;  // swizzled read slot (ushorts)

#define ESTAGE(K0, BUF) do { \
    gl16(srcA0 + (K0), &As[BUF][cc0 * 512]); \
    gl16(srcA1 + (K0), &As[BUF][cc0 * 512 + 512]); \
    gl16(srcB0 + (K0), &Bs[BUF][cc0 * 512]); \
    gl16(srcB1 + (K0), &Bs[BUF][cc0 * 512 + 512]); \
  } while (0)

  ESTAGE(0, 0);
  ESTAGE(32, 1);
  for (int k0 = 0, t = 0; k0 < HID; k0 += 32, ++t) {
    if (k0 + 32 < HID) asm volatile("s_waitcnt vmcnt(4)" ::: "memory");
    else               asm volatile("s_waitcnt vmcnt(0)" ::: "memory");
    __builtin_amdgcn_s_barrier();
    asm volatile("" ::: "memory");
    const ushort* as = As[t & 1];
    const ushort* bs = Bs[t & 1];
    bf16x8 av[4], bv[4];
#pragma unroll
    for (int m = 0; m < 4; m++)
      av[m] = *reinterpret_cast<const bf16x8*>(&as[(wm * 64 + m * 16 + fr) * 32 + sa]);
#pragma unroll
    for (int n = 0; n < 4; n++)
      bv[n] = *reinterpret_cast<const bf16x8*>(&bs[(wn * 64 + n * 16 + fr) * 32 + sa]);
#pragma unroll
    for (int m = 0; m < 4; m++)
#pragma unroll
      for (int n = 0; n < 4; n++)
        acc[m][n] = __builtin_amdgcn_mfma_f32_16x16x32_bf16(av[m], bv[n], acc[m][n], 0, 0, 0);
    asm volatile("" ::: "memory");
    __builtin_amdgcn_s_barrier();
    if (k0 + 64 < HID) ESTAGE(k0 + 64, t & 1);
  }
#undef ESTAGE

  const int colb = ct * 128 + wn * 64 + fr;
  float bc[4];
#pragma unroll
  for (int n = 0; n < 4; n++) bc[n] = bias[e * HID + colb + n * 16];
#pragma unroll
  for (int m = 0; m < 4; m++) {
#pragma unroll
    for (int rr = 0; rr < 4; rr++) {
      int r = rt * 128 + wm * 64 + m * 16 + fq * 4 + rr;
      if (r < count) {
        int ent = list[e * CAP + r];
        int tok = ent & 0xFFFF;
        int slot = (ent >> 16) & 1;
        float wgt = listw[e * CAP + r];
        ushort* dst = contrib + ((size_t)slot * NTOK + tok) * HID;
#pragma unroll
        for (int n = 0; n < 4; n++) {
          float v = acc[m][n][rr] + bc[n];
          float sv = v / (1.0f + __expf(-v));
          dst[colb + n * 16] = f2bf(sv * wgt);
        }
      }
    }
  }
}

// ---------------- combine GEMM with fused mix (A = c0+c1, reg-staged) ----------------
__global__ __launch_bounds__(256) void cgemm_kernel(
    const ushort* __restrict__ Cb, const ushort* __restrict__ Bb,
    float* __restrict__ outp) {
  __shared__ ushort As[2][128 * 32];
  __shared__ ushort Bs[2][128 * 32];
  const int tid = threadIdx.x, lane = tid & 63, wave = tid >> 6;
  const int p = blockIdx.x;
  const int cx = p & 7, q = p >> 3, ct = q & 7, rt = ((q >> 3) << 3) | cx;  // rt < 128

  const int cc0 = wave * 2;
  const int rl0 = cc0 * 16 + (lane >> 2);
  const int rl1 = rl0 + 16;
  const int nat8 = (lane & 3) * 8;
  const int swz8 = (((lane & 3) ^ ((lane >> 3) & 3))) * 8;

  // B via gl16: pre-swizzled source, linear dest
  const ushort* srcB0 = Bb + (size_t)(ct * 128 + rl0) * HID + swz8;
  const ushort* srcB1 = Bb + (size_t)(ct * 128 + rl1) * HID + swz8;
  // A via registers: natural source col, swizzled ds_write slot
  const ushort* sA0c0 = Cb + (size_t)(rt * 128 + rl0) * HID + nat8;
  const ushort* sA0c1 = sA0c0 + (size_t)NTOK * HID;
  const ushort* sA1c0 = Cb + (size_t)(rt * 128 + rl1) * HID + nat8;
  const ushort* sA1c1 = sA1c0 + (size_t)NTOK * HID;
  const int wA0 = rl0 * 32 + swz8;   // ds_write addrs (ushorts)
  const int wA1 = rl1 * 32 + swz8;

  f32x4 acc[4][4];
#pragma unroll
  for (int m = 0; m < 4; m++)
#pragma unroll
    for (int n = 0; n < 4; n++) acc[m][n] = (f32x4){0.f, 0.f, 0.f, 0.f};

  const int wm = wave >> 1, wn = wave & 1;
  const int fr = lane & 15, fq = lane >> 4;
  const int sa = (fq ^ ((fr >> 1) & 3)) * 8;

  auto bfadd8 = [](short8 a, short8 b) {
    short8 o;
#pragma unroll
    for (int j = 0; j < 8; j++)
      o[j] = (short)f2bf(bf2f((ushort)a[j]) + bf2f((ushort)b[j]));
    return o;
  };

  // prologue: tile 0 fully staged
  gl16(srcB0, &Bs[0][cc0 * 512]);
  gl16(srcB1, &Bs[0][cc0 * 512 + 512]);
  {
    short8 a0 = *reinterpret_cast<const short8*>(sA0c0);
    short8 b0 = *reinterpret_cast<const short8*>(sA0c1);
    short8 a1 = *reinterpret_cast<const short8*>(sA1c0);
    short8 b1 = *reinterpret_cast<const short8*>(sA1c1);
    *reinterpret_cast<short8*>(&As[0][wA0]) = bfadd8(a0, b0);
    *reinterpret_cast<short8*>(&As[0][wA1]) = bfadd8(a1, b1);
  }
  __syncthreads();
  // issue tile 1
  gl16(srcB0 + 32, &Bs[1][cc0 * 512]);
  gl16(srcB1 + 32, &Bs[1][cc0 * 512 + 512]);
  short8 na0 = *reinterpret_cast<const short8*>(sA0c0 + 32);
  short8 nb0 = *reinterpret_cast<const short8*>(sA0c1 + 32);
  short8 na1 = *reinterpret_cast<const short8*>(sA1c0 + 32);
  short8 nb1 = *reinterpret_cast<const short8*>(sA1c1 + 32);

  for (int k0 = 0, t = 0; k0 < HID; k0 += 32, ++t) {
    const ushort* as = As[t & 1];
    const ushort* bs = Bs[t & 1];
    bf16x8 av[4], bv[4];
#pragma unroll
    for (int m = 0; m < 4; m++)
      av[m] = *reinterpret_cast<const bf16x8*>(&as[(wm * 64 + m * 16 + fr) * 32 + sa]);
#pragma unroll
    for (int n = 0; n < 4; n++)
      bv[n] = *reinterpret_cast<const bf16x8*>(&bs[(wn * 64 + n * 16 + fr) * 32 + sa]);
#pragma unroll
    for (int m = 0; m < 4; m++)
#pragma unroll
      for (int n = 0; n < 4; n++)
        acc[m][n] = __builtin_amdgcn_mfma_f32_16x16x32_bf16(av[m], bv[n], acc[m][n], 0, 0, 0);
    if (k0 + 32 < HID) {  // write tile t+1 A into other buffer (loads overlap MFMA above)
      *reinterpret_cast<short8*>(&As[(t + 1) & 1][wA0]) = bfadd8(na0, nb0);
      *reinterpret_cast<short8*>(&As[(t + 1) & 1][wA1]) = bfadd8(na1, nb1);
    }
    __syncthreads();
    if (k0 + 64 < HID) {  // issue tile t+2 (after barrier: buf[t&1] free)
      gl16(srcB0 + k0 + 64, &Bs[t & 1][cc0 * 512]);
      gl16(srcB1 + k0 + 64, &Bs[t & 1][cc0 * 512 + 512]);
      na0 = *reinterpret_cast<const short8*>(sA0c0 + k0 + 64);
      nb0 = *reinterpret_cast<const short8*>(sA0c1 + k0 + 64);
      na1 = *reinterpret_cast<const short8*>(sA1c0 + k0 + 64);
      nb1 = *reinterpret_cast<const short8*>(sA1c1 + k0 + 64);
    }
  }

  const int colb = ct * 128 + wn * 64 + fr;
#pragma unroll
  for (int m = 0; m < 4; m++)
#pragma unroll
    for (int rr = 0; rr < 4; rr++) {
      int r = rt * 128 + wm * 64 + m * 16 + fq * 4 + rr;
      float* dst = outp + (size_t)r * HID;
#pragma unroll
      for (int n = 0; n < 4; n++) dst[colb + n * 16] = acc[m][n][rr];
    }
}

extern "C" void kernel_launch(void* const* d_in, const int* in_sizes, int n_in,
                              void* d_out, int out_size, void* d_ws, size_t ws_size,
                              hipStream_t stream) {
  const float* tokens    = (const float*)d_in[0];
  const float* gate_w    = (const float*)d_in[1];
  const float* expert_w  = (const float*)d_in[2];
  const float* expert_b  = (const float*)d_in[3];
  const float* combine_w = (const float*)d_in[4];
  float* outp = (float*)d_out;

  char* p = (char*)d_ws;
  ushort* Xb  = (ushort*)p; p += (size_t)NTOK * HID * 2;        // 33.5 MB
  ushort* Wxb = (ushort*)p; p += (size_t)NEXP * HID * HID * 2;  // 16.8 MB
  ushort* Wcb = (ushort*)p; p += (size_t)HID * HID * 2;         //  2.1 MB
  ushort* ctb = (ushort*)p; p += (size_t)2 * NTOK * HID * 2;    // 67.1 MB
  int*   list = (int*)p;    p += (size_t)NEXP * CAP * 4;
  float* lsw  = (float*)p;  p += (size_t)NEXP * CAP * 4;
  int*   cnts = (int*)p;    p += 256;
  uint32_t* tinfo = (uint32_t*)p; p += (size_t)NTOK * 4;
  float2*   twp   = (float2*)p;   p += (size_t)NTOK * 8;

  zero_kernel<<<1, 64, 0, stream>>>(cnts);
  gate_kernel<<<2048, 256, 0, stream>>>(tokens, gate_w, Xb, tinfo, twp);
  cvt_kernel<<<1024, 256, 0, stream>>>(expert_w, Wxb, NEXP * HID * HID / 4);
  cvt_kernel<<<256, 256, 0, stream>>>(combine_w, Wcb, HID * HID / 4);
  scatter_kernel<<<64, 256, 0, stream>>>(tinfo, twp, list, lsw, cnts);
  egemm_kernel<<<4096, 256, 0, stream>>>(Xb, Wxb, expert_b, list, lsw, cnts, ctb);
  cgemm_kernel<<<1024, 256, 0, stream>>>(ctb, Wcb, outp);
}